// Round 6
// baseline (1574.431 us; speedup 1.0000x reference)
//
#include <hip/hip_runtime.h>
#include <stdint.h>

#define CDIV(a,b) (((a)+(b)-1)/(b))

typedef unsigned short u16;
using bf16x8   = __attribute__((ext_vector_type(8))) short;
using floatx4  = __attribute__((ext_vector_type(4))) float;
using floatx16 = __attribute__((ext_vector_type(16))) float;

constexpr int B_N   = 2048;   // batch
constexpr int IN_N  = 784;
constexpr int H_N   = 512;
constexpr int OUT_N = 512;
constexpr int E_N   = 8;
constexpr int ER_N  = 4;      // recurrent experts
constexpr int ES_N  = 4;      // simple experts
constexpr int T_N   = 28;
constexpr int F_N   = 28;
constexpr int G4H   = 2048;   // 4*H
constexpr int KA    = 544;    // 512 (h) + 28 (x_t) + 4 pad
constexpr int KB8   = KA / 8; // 68 k8-blocks
constexpr int NKI   = KA / 16;// 34 mfma k-iters
constexpr int XP    = 800;    // 784 padded

__device__ __forceinline__ u16 f2bf(float f) {
  union { float f; uint32_t u; } v; v.f = f;
  uint32_t r = v.u + 0x7fffu + ((v.u >> 16) & 1u);   // RNE
  return (u16)(r >> 16);
}
__device__ __forceinline__ float sigm(float x)  { return 1.f / (1.f + __expf(-x)); }
__device__ __forceinline__ float tanhf_(float x){ return 1.f - 2.f / (__expf(2.f * x) + 1.f); }

__device__ __forceinline__ void async16(const void* g, void* l) {
  __builtin_amdgcn_global_load_lds(
      (__attribute__((address_space(1))) void*)g,
      (__attribute__((address_space(3))) void*)l, 16, 0, 0);
}

// ============ weight-stationary LSTM step, v3 (expert-per-XCD-pair) ============
// 512 blocks x 512 threads, 2 blocks/CU (69.6 KB LDS, <=128 unified regs).
// Block decode puts expert z on XCD pair {2z, 2z+1} (assuming XCD = blk&7
// round-robin): xcd=blk&7, j=blk>>3, z=xcd>>1, nt=2*(j&15)+(xcd&1), mr=j>>4.
//  - A slice of expert z (8.9/4 MB) is read by blocks on only 2 XCDs -> L2-hit
//    after first reader (A re-read amplification served by L2, not LLC).
//  - The 4 mr-copies of W slice (z,nt) share one XCD (nt parity) -> W LLC
//    traffic ~= unique 8.9 MB/step.
// Block owns expert z, h-cols [16*nt,+16), batch rows [512*mr,+512).
// W slice = 2 packed 32-row n-tiles x KA: tile0=[i(h0..15)|f(h0..15)],
// tile1=[g|o], B-frag layout [j][k8][ln 32][e8 8] in LDS.
// Epilogue: lo lanes (col<16) own gate i/g, hi lanes f/o of the SAME h;
// transcendentals split lo/hi, recombined with one __shfl_xor(16) pair.
__global__ __launch_bounds__(512, 4)
void lstm_step(const u16* __restrict__ Wc, const float* __restrict__ bq,
               const u16* __restrict__ xb, const u16* __restrict__ Ain,
               u16* __restrict__ Aout, float* __restrict__ Cst,
               u16* __restrict__ Hlast, int t)
{
  extern __shared__ __align__(16) u16 Ws[];   // 2*KB8*256 u16 = 69632 B
  const int tid  = threadIdx.x;
  const int lane = tid & 63;
  const int wave = tid >> 6;
  const int blk  = blockIdx.x;
  const int xcd  = blk & 7;
  const int j    = blk >> 3;
  const int z    = xcd >> 1;
  const int nt   = 2 * (j & 15) + (xcd & 1);
  const int mr   = j >> 4;
  const int s    = z * 32 + nt;
  const int ln   = lane & 31;
  const int hw   = lane >> 5;

  const int mblk0 = mr * 16 + wave * 2;
  const size_t zoff = (size_t)z * ((size_t)64 * KB8 * 256);
  const u16* Az = Ain + zoff;

  const u16* Ap0 = Az + ((size_t)mblk0 * KB8 + hw) * 256 + ln * 8;
  const u16* Ap1 = Az + ((size_t)(mblk0 + 1) * KB8 + hw) * 256 + ln * 8;

  // depth-2 A prefetch pipeline (issue before W barrier to overlap)
  bf16x8 pa0[2], pa1[2];
  pa0[0] = *(const bf16x8*)Ap0;          pa1[0] = *(const bf16x8*)Ap1;
  pa0[1] = *(const bf16x8*)(Ap0 + 512);  pa1[1] = *(const bf16x8*)(Ap1 + 512);

  // stage W slice (69632 B) into LDS (last partial pass is waves 0-3, uniform)
  {
    const u16* Wsrc = Wc + (size_t)s * (2 * KB8 * 256);
    for (int off = tid * 8; off < 2 * KB8 * 256; off += 512 * 8)
      async16(Wsrc + off, Ws + off);
  }
  __syncthreads();

  floatx16 acc[2][2] = {};
#pragma unroll 2
  for (int kk = 0; kk < NKI; ++kk) {
    bf16x8 a0 = pa0[kk & 1], a1 = pa1[kk & 1];
    if (kk + 2 < NKI) {
      pa0[kk & 1] = *(const bf16x8*)(Ap0 + (size_t)(kk + 2) * 512);
      pa1[kk & 1] = *(const bf16x8*)(Ap1 + (size_t)(kk + 2) * 512);
    }
    const u16* Bp = Ws + (2 * kk + hw) * 256 + ln * 8;
    bf16x8 b0 = *(const bf16x8*)(Bp);                 // [i|f] tile
    bf16x8 b1 = *(const bf16x8*)(Bp + KB8 * 256);     // [g|o] tile
    acc[0][0] = __builtin_amdgcn_mfma_f32_32x32x16_bf16(a0, b0, acc[0][0], 0, 0, 0);
    acc[0][1] = __builtin_amdgcn_mfma_f32_32x32x16_bf16(a0, b1, acc[0][1], 0, 0, 0);
    acc[1][0] = __builtin_amdgcn_mfma_f32_32x32x16_bf16(a1, b0, acc[1][0], 0, 0, 0);
    acc[1][1] = __builtin_amdgcn_mfma_f32_32x32x16_bf16(a1, b1, acc[1][1], 0, 0, 0);
  }

  // ---- cell epilogue: split transcendental work lo/hi, one shfl pair ----
  const int hloc = ln & 15;
  const int hcol = nt * 16 + hloc;
  const bool lo  = (ln < 16);
  floatx4 bias = ((const floatx4*)bq)[z * H_N + hcol];   // (bi,bf,bg,bo)
  const float bA = lo ? bias[0] : bias[1];   // i | f
  const float bB = lo ? bias[2] : bias[3];   // g | o
  const int last = (t == T_N - 1);
  u16* Aoz = Aout + zoff;
  const int wgid = blk * 8 + wave;

#pragma unroll
  for (int i = 0; i < 2; ++i) {
    const int mb = mblk0 + i;
    // c layout: [wgid][i][r 16][slot 32]; slot = hw*16 + hloc (lo lanes own c)
    float* Cb = Cst + (((size_t)wgid * 2 + i) * 16) * 32 + hw * 16 + hloc;
#pragma unroll
    for (int r = 0; r < 16; ++r) {
      float pa = acc[i][0][r] + bA;          // lo: i-pre, hi: f-pre (same h)
      float pb = acc[i][1][r] + bB;          // lo: g-pre, hi: o-pre
      float ea = 1.f / (1.f + __expf(-pa));  // σ(i) | σ(f)
      float xx = lo ? (2.f * pb) : (-pb);
      float ex = __expf(xx);
      float iv = 1.f / (1.f + ex);
      float eb = lo ? (1.f - 2.f * iv) : iv; // tanh(g) | σ(o)
      float fa = __shfl_xor(ea, 16);         // lo receives σ(f)
      float fb = __shfl_xor(eb, 16);         // lo receives σ(o)
      float cprev = (t == 0) ? 0.f : Cb[r * 32];
      if (lo) {
        float c = fa * cprev + ea * eb;
        Cb[r * 32] = c;
        u16 hb = f2bf(fb * tanhf_(c));
        int mrow = 4 * hw + (r & 3) + 8 * (r >> 2);  // 32x32 C/D row mapping
        if (!last)
          Aoz[((size_t)mb * KB8 + (hcol >> 3)) * 256 + mrow * 8 + (hcol & 7)] = hb;
        else
          Hlast[((size_t)(z * B_N + mb * 32 + mrow)) * H_N + hcol] = hb;
      }
    }
  }

  // ---- stage x_{t+1} slice (k in [512,540)) into Aout: nt==0 blocks only ----
  if (nt == 0 && t + 1 < T_N) {
    for (int idx = tid; idx < 512 * F_N; idx += 512) {
      int ml  = idx / F_N, col = idx - ml * F_N;
      int m   = mr * 512 + ml;
      int k   = H_N + col;
      Aoz[((size_t)(m >> 5) * KB8 + (k >> 3)) * 256 + (m & 31) * 8 + (k & 7)] =
          xb[(size_t)m * XP + (t + 1) * F_N + col];
    }
  }
}

// ============ generic GEMM (tail): C[z] = A[z] @ B[z]^T + bias[z] ============
template<int RELU, int OBF>
__global__ __launch_bounds__(256, 2)
void gemm_bt(const u16* __restrict__ A, int lda, long sAz,
             const u16* __restrict__ Bw, int ldb, long sBz,
             const float* __restrict__ bias, int sBiz,
             void* __restrict__ Cv, int ldc, long sCz,
             int K)
{
  __shared__ __align__(16) u16 As[128 * 32];
  __shared__ __align__(16) u16 Bs[128 * 32];
  const int tid  = threadIdx.x;
  const int lane = tid & 63;
  const int wave = tid >> 6;
  const int m0 = blockIdx.y * 128;
  const int n0 = blockIdx.x * 128;
  const int z  = blockIdx.z;
  const u16* Ab = A  + (size_t)z * sAz;
  const u16* Bb = Bw + (size_t)z * sBz;

  const int wm   = (wave & 1) * 64;
  const int wn   = (wave >> 1) * 64;
  const int lm   = lane & 15;
  const int quad = lane >> 4;

  const int s0 = wave * 64 + lane;
  const int r0 = s0 >> 2, c0 = (s0 & 3) * 8;
  const int s1 = s0 + 256;
  const int r1 = s1 >> 2, c1 = (s1 & 3) * 8;

  floatx4 acc[4][4] = {};

  for (int k0 = 0; k0 < K; k0 += 32) {
    async16(Ab + (size_t)(m0 + r0) * lda + (k0 + c0), As + wave * 512);
    async16(Ab + (size_t)(m0 + r1) * lda + (k0 + c1), As + 2048 + wave * 512);
    async16(Bb + (size_t)(n0 + r0) * ldb + (k0 + c0), Bs + wave * 512);
    async16(Bb + (size_t)(n0 + r1) * ldb + (k0 + c1), Bs + 2048 + wave * 512);
    __syncthreads();
    bf16x8 af[4], bf_[4];
#pragma unroll
    for (int i = 0; i < 4; ++i)
      af[i] = *(const bf16x8*)&As[(wm + i * 16 + lm) * 32 + quad * 8];
#pragma unroll
    for (int j = 0; j < 4; ++j)
      bf_[j] = *(const bf16x8*)&Bs[(wn + j * 16 + lm) * 32 + quad * 8];
#pragma unroll
    for (int i = 0; i < 4; ++i)
#pragma unroll
      for (int j = 0; j < 4; ++j)
        acc[i][j] = __builtin_amdgcn_mfma_f32_16x16x32_bf16(af[i], bf_[j], acc[i][j], 0, 0, 0);
    __syncthreads();
  }

  float bj[4];
#pragma unroll
  for (int j = 0; j < 4; ++j)
    bj[j] = bias ? bias[z * sBiz + n0 + wn + j * 16 + lm] : 0.f;

#pragma unroll
  for (int i = 0; i < 4; ++i) {
#pragma unroll
    for (int r = 0; r < 4; ++r) {
      int m = m0 + wm + i * 16 + quad * 4 + r;
      size_t row = (size_t)z * sCz + (size_t)m * ldc;
#pragma unroll
      for (int j = 0; j < 4; ++j) {
        int n = n0 + wn + j * 16 + lm;
        float v = acc[i][j][r] + bj[j];
        if (RELU) v = fmaxf(v, 0.f);
        if (OBF) ((u16*)Cv)[row + n] = f2bf(v);
        else     ((float*)Cv)[row + n] = v;
      }
    }
  }
}

// ============ gate: softmax(scores/e), top-5, renormalize. one wave per row ============
__global__ __launch_bounds__(256)
void gate_k(const float* __restrict__ x, const float* __restrict__ Wg,
            const float* __restrict__ bg, float* __restrict__ Wt)
{
  int lane = threadIdx.x & 63;
  int row  = blockIdx.x * 4 + (threadIdx.x >> 6);
  float ps[E_N];
#pragma unroll
  for (int e = 0; e < E_N; ++e) ps[e] = 0.f;
  const float* xr = x + (size_t)row * IN_N;
  for (int k = lane; k < IN_N; k += 64) {
    float xv = xr[k];
#pragma unroll
    for (int e = 0; e < E_N; ++e) ps[e] += xv * Wg[e * IN_N + k];
  }
#pragma unroll
  for (int e = 0; e < E_N; ++e) {
#pragma unroll
    for (int off = 32; off >= 1; off >>= 1) ps[e] += __shfl_down(ps[e], off);
  }
  if (lane == 0) {
    float s[E_N], mx = -1e30f;
#pragma unroll
    for (int e = 0; e < E_N; ++e) { s[e] = (ps[e] + bg[e]) * 0.36787944117144233f; mx = fmaxf(mx, s[e]); }
    float pr[E_N], sum = 0.f;
#pragma unroll
    for (int e = 0; e < E_N; ++e) { pr[e] = __expf(s[e] - mx); sum += pr[e]; }
    float inv = 1.f / sum;
#pragma unroll
    for (int e = 0; e < E_N; ++e) pr[e] *= inv;
    unsigned used = 0; float wsum = 0.f;
    for (int k = 0; k < 5; ++k) {
      int am = -1; float bv = -1.f;
      for (int e = 0; e < E_N; ++e)
        if (!((used >> e) & 1) && pr[e] > bv) { bv = pr[e]; am = e; }
      used |= 1u << am; wsum += pr[am];
    }
    float winv = 1.f / (wsum + 1e-8f);
    for (int e = 0; e < E_N; ++e)
      Wt[row * E_N + e] = ((used >> e) & 1) ? pr[e] * winv : 0.f;
  }
}

// ============ combine ============
__global__ __launch_bounds__(256)
void combine_k(const float* __restrict__ O, const float* __restrict__ Wt, float* __restrict__ out)
{
  int idx = blockIdx.x * 256 + threadIdx.x;
  if (idx >= B_N * OUT_N) return;
  int b = idx / OUT_N;
  float a = 0.f;
#pragma unroll
  for (int e = 0; e < E_N; ++e)
    a += Wt[b * E_N + e] * O[(size_t)e * B_N * OUT_N + idx];
  out[idx] = a;
}

// ============ prep kernels ============
__global__ void prep_x_k(const float* __restrict__ x, u16* __restrict__ xb) {
  int idx = blockIdx.x * 256 + threadIdx.x;
  if (idx >= B_N * XP) return;
  int k = idx % XP, b = idx / XP;
  xb[idx] = f2bf(k < IN_N ? x[(size_t)b * IN_N + k] : 0.f);
}
// W packed layout: [s = z*32+nt][j 2][k8][ln 32][e8 8];
// tile j=0: ln<16 -> gate i of h=nt*16+ln, ln>=16 -> gate f of h-16; j=1: g|o.
__global__ void prep_wfrag_k(const float* __restrict__ Whh, const float* __restrict__ Wih,
                             u16* __restrict__ Wc) {
  int idx = blockIdx.x * 256 + threadIdx.x;
  if (idx >= ER_N * G4H * KA) return;
  int e8 = idx & 7, ln = (idx >> 3) & 31;
  int k8 = (idx >> 8) % KB8;
  int rest = (idx >> 8) / KB8;
  int j = rest & 1, sm = rest >> 1;           // sm = z*32+nt
  int z = sm >> 5, nt = sm & 31;
  int gate = j * 2 + (ln >= 16 ? 1 : 0);
  int h = nt * 16 + (ln & 15);
  int k = k8 * 8 + e8;
  int g = gate * H_N + h;
  float v = 0.f;
  if (k < H_N)            v = Whh[((size_t)(z * G4H + g)) * H_N + k];
  else if (k < H_N + F_N) v = Wih[((size_t)(z * G4H + g)) * F_N + (k - H_N)];
  Wc[idx] = f2bf(v);
}
// bias quad layout: [z][h][gate 4] floats (one float4 per (z,h))
__global__ void prep_bq_k(const float* __restrict__ bih, const float* __restrict__ bhh,
                          float* __restrict__ o) {
  int idx = blockIdx.x * 256 + threadIdx.x;
  if (idx >= ER_N * H_N * 4) return;
  int gate = idx & 3, h = (idx >> 2) & (H_N - 1), z = idx >> 11;
  int g = z * G4H + gate * H_N + h;
  o[idx] = bih[g] + bhh[g];
}
__global__ void cvt_k(const float* __restrict__ in, u16* __restrict__ o, int n) {
  int idx = blockIdx.x * 256 + threadIdx.x;
  if (idx < n) o[idx] = f2bf(in[idx]);
}
__global__ void prep_w1_k(const float* __restrict__ W1, u16* __restrict__ o) {
  int idx = blockIdx.x * 256 + threadIdx.x;
  if (idx >= ES_N * H_N * XP) return;
  int k = idx % XP; int r = idx / XP;
  o[idx] = f2bf(k < IN_N ? W1[(size_t)r * IN_N + k] : 0.f);
}
// A buffers in frag layout [z][mb 64][k8 68][mrow 32][e8 8]; A0 gets x_0, rest 0
__global__ void init_Afrag_k(u16* __restrict__ A0, u16* __restrict__ A1,
                             const u16* __restrict__ xb) {
  int idx = blockIdx.x * 256 + threadIdx.x;
  if (idx >= ER_N * B_N * KA) return;
  int e8 = idx & 7, mrow = (idx >> 3) & 31;
  int k8 = (idx >> 8) % KB8;
  int mb = ((idx >> 8) / KB8) & 63;
  int k = k8 * 8 + e8, m = mb * 32 + mrow;
  u16 v = 0;
  if (k >= H_N && k < H_N + F_N) v = xb[(size_t)m * XP + (k - H_N)];
  A0[idx] = v;
  A1[idx] = 0;
}

extern "C" void kernel_launch(void* const* d_in, const int* in_sizes, int n_in,
                              void* d_out, int out_size, void* d_ws, size_t ws_size,
                              hipStream_t stream) {
  const float* x   = (const float*)d_in[0];
  const float* Wg  = (const float*)d_in[1];
  const float* bg  = (const float*)d_in[2];
  const float* Wih = (const float*)d_in[3];
  const float* Whh = (const float*)d_in[4];
  const float* bih = (const float*)d_in[5];
  const float* bhh = (const float*)d_in[6];
  const float* fcW = (const float*)d_in[7];
  const float* fcb = (const float*)d_in[8];
  const float* W1  = (const float*)d_in[9];
  const float* b1  = (const float*)d_in[10];
  const float* W2  = (const float*)d_in[11];
  const float* b2  = (const float*)d_in[12];
  float* out = (float*)d_out;

  char* p = (char*)d_ws;
  auto take = [&](size_t bytes) { void* q = (void*)p; p += (bytes + 255) & ~(size_t)255; return q; };
  u16*   xb    = (u16*)  take((size_t)B_N * XP * 2);
  u16*   Wc    = (u16*)  take((size_t)ER_N * G4H * KA * 2);
  float* bq    = (float*)take((size_t)ER_N * H_N * 4 * 4);
  u16*   fcWb  = (u16*)  take((size_t)ER_N * OUT_N * H_N * 2);
  u16*   W1b   = (u16*)  take((size_t)ES_N * H_N * XP * 2);
  u16*   W2b   = (u16*)  take((size_t)ES_N * OUT_N * H_N * 2);
  u16*   A0    = (u16*)  take((size_t)ER_N * B_N * KA * 2);
  u16*   A1    = (u16*)  take((size_t)ER_N * B_N * KA * 2);
  float* Cst   = (float*)take((size_t)ER_N * B_N * H_N * 4);
  u16*   Hlast = (u16*)  take((size_t)ER_N * B_N * H_N * 2);
  u16*   H1    = (u16*)  take((size_t)ES_N * B_N * H_N * 2);
  float* Ob    = (float*)take((size_t)E_N * B_N * OUT_N * 4);
  float* Wgt   = (float*)take((size_t)B_N * E_N * 4);

  dim3 blk(256);
  prep_x_k    <<<CDIV(B_N * XP, 256),           blk, 0, stream>>>(x, xb);
  prep_wfrag_k<<<CDIV(ER_N * G4H * KA, 256),    blk, 0, stream>>>(Whh, Wih, Wc);
  prep_bq_k   <<<CDIV(ER_N * H_N * 4, 256),     blk, 0, stream>>>(bih, bhh, bq);
  cvt_k       <<<CDIV(ER_N * OUT_N * H_N, 256), blk, 0, stream>>>(fcW, fcWb, ER_N * OUT_N * H_N);
  prep_w1_k   <<<CDIV(ES_N * H_N * XP, 256),    blk, 0, stream>>>(W1, W1b);
  cvt_k       <<<CDIV(ES_N * OUT_N * H_N, 256), blk, 0, stream>>>(W2, W2b, ES_N * OUT_N * H_N);
  init_Afrag_k<<<CDIV(ER_N * B_N * KA, 256),    blk, 0, stream>>>(A0, A1, xb);
  gate_k      <<<B_N / 4,                       blk, 0, stream>>>(x, Wg, bg, Wgt);

  // ---- LSTM: 28 weight-stationary dispatches, ping-pong A ----
  constexpr unsigned ldsBytes = 2u * KB8 * 256u * 2u;   // 69632
  hipFuncSetAttribute((const void*)lstm_step,
                      hipFuncAttributeMaxDynamicSharedMemorySize, ldsBytes);
  for (int t = 0; t < T_N; ++t) {
    const u16* Ar = (t & 1) ? A1 : A0;
    u16*       Aw = (t & 1) ? A0 : A1;
    lstm_step<<<dim3(512), dim3(512), ldsBytes, stream>>>(
        Wc, bq, xb, Ar, Aw, Cst, Hlast, t);
  }

  // ---- fc on h_last -> Ob[0..3] ----
  gemm_bt<0, 0><<<dim3(OUT_N / 128, B_N / 128, ER_N), blk, 0, stream>>>(
      Hlast, H_N, (long)B_N * H_N,
      fcWb, H_N, (long)OUT_N * H_N,
      fcb, OUT_N,
      (void*)Ob, OUT_N, (long)B_N * OUT_N, H_N);

  // ---- simple experts ----
  gemm_bt<1, 1><<<dim3(H_N / 128, B_N / 128, ES_N), blk, 0, stream>>>(
      xb, XP, 0L,
      W1b, XP, (long)H_N * XP,
      b1, H_N,
      (void*)H1, H_N, (long)B_N * H_N, XP);
  gemm_bt<0, 0><<<dim3(OUT_N / 128, B_N / 128, ES_N), blk, 0, stream>>>(
      H1, H_N, (long)B_N * H_N,
      W2b, H_N, (long)OUT_N * H_N,
      b2, OUT_N,
      (void*)(Ob + (size_t)ER_N * B_N * OUT_N), OUT_N, (long)B_N * OUT_N, H_N);

  combine_k<<<CDIV(B_N * OUT_N, 256), blk, 0, stream>>>(Ob, Wgt, out);
}

// Round 7
// 1179.122 us; speedup vs baseline: 1.3353x; 1.3353x over previous
//
#include <hip/hip_runtime.h>
#include <stdint.h>

#define CDIV(a,b) (((a)+(b)-1)/(b))

typedef unsigned short u16;
using bf16x8   = __attribute__((ext_vector_type(8))) short;
using floatx4  = __attribute__((ext_vector_type(4))) float;
using floatx16 = __attribute__((ext_vector_type(16))) float;

constexpr int B_N   = 2048;   // batch
constexpr int IN_N  = 784;
constexpr int H_N   = 512;
constexpr int OUT_N = 512;
constexpr int E_N   = 8;
constexpr int ER_N  = 4;      // recurrent experts
constexpr int ES_N  = 4;      // simple experts
constexpr int T_N   = 28;
constexpr int F_N   = 28;
constexpr int G4H   = 2048;   // 4*H
constexpr int KA    = 544;    // 512 (h) + 28 (x_t) + 4 pad
constexpr int KB8   = KA / 8; // 68 k8-blocks
constexpr int NKI   = KA / 16;// 34 mfma k-iters
constexpr int XP    = 800;    // 784 padded

__device__ __forceinline__ u16 f2bf(float f) {
  union { float f; uint32_t u; } v; v.f = f;
  uint32_t r = v.u + 0x7fffu + ((v.u >> 16) & 1u);   // RNE
  return (u16)(r >> 16);
}
__device__ __forceinline__ float sigm(float x)  { return 1.f / (1.f + __expf(-x)); }
__device__ __forceinline__ float tanhf_(float x){ return 1.f - 2.f / (__expf(2.f * x) + 1.f); }

__device__ __forceinline__ void async16(const void* g, void* l) {
  __builtin_amdgcn_global_load_lds(
      (__attribute__((address_space(1))) void*)g,
      (__attribute__((address_space(3))) void*)l, 16, 0, 0);
}

// ============ weight-stationary LSTM step, v4 ============
// R4 partition + XCD swizzle + depth-4 A prefetch.
// 256 blocks x 512 threads, 1 block/CU (139 KB LDS, 2 waves/SIMD, <=256 regs).
// Decode (XCD = blk&7 round-robin): xcd=blk&7, j=blk>>3, z=xcd>>1,
// nt=(j&7)*2+(xcd&1), mr=j>>3. Expert z lives on XCD pair {2z,2z+1};
// the 4 mr-copies of W slice (z,nt) share one XCD.
// Block owns expert z, h-cols [32*nt,+32), batch rows [512*mr,+512).
// W slice = 4 gate-tiles (i,f,g,o) of 32 rows x KA in LDS, B-frag layout
// [j 4][k8][ln 32][e8 8]. Wave: 2 m-blocks x 4 gate-tiles -> 8 MFMA per
// 2 A-loads per k-iter (best measured MFMA:load ratio).
// A-frag loads use a depth-4 register ring to cover ~400cyc LLC latency.
__global__ __launch_bounds__(512, 2)
void lstm_step(const u16* __restrict__ Wc, const float* __restrict__ brec,
               const u16* __restrict__ xb, const u16* __restrict__ Ain,
               u16* __restrict__ Aout, float* __restrict__ Cst,
               u16* __restrict__ Hlast, int t)
{
  extern __shared__ __align__(16) u16 Ws[];   // 4*KB8*256 u16 = 139264 B
  const int tid  = threadIdx.x;
  const int lane = tid & 63;
  const int wave = tid >> 6;
  const int blk  = blockIdx.x;
  const int xcd  = blk & 7;
  const int j8   = blk >> 3;
  const int z    = xcd >> 1;
  const int nt   = (j8 & 7) * 2 + (xcd & 1);
  const int mr   = j8 >> 3;
  const int ln   = lane & 31;
  const int hw   = lane >> 5;

  const int mblk0 = mr * 16 + wave * 2;
  const size_t zoff = (size_t)z * ((size_t)64 * KB8 * 256);
  const u16* Az = Ain + zoff;

  const u16* Ap0 = Az + ((size_t)mblk0 * KB8 + hw) * 256 + ln * 8;
  const u16* Ap1 = Az + ((size_t)(mblk0 + 1) * KB8 + hw) * 256 + ln * 8;

  // ---- depth-4 A prefetch ring: issue before W staging so they land first ----
  bf16x8 pa0[4], pa1[4];
#pragma unroll
  for (int d = 0; d < 4; ++d) {
    pa0[d] = *(const bf16x8*)(Ap0 + (size_t)d * 512);
    pa1[d] = *(const bf16x8*)(Ap1 + (size_t)d * 512);
  }

  // ---- stage W slice (139264 B) into LDS: 17 x 1KB async chunks per wave ----
  {
    const u16* Wsrc = Wc + (size_t)(z * 16 + nt) * (4 * KB8 * 256);
    const int base = wave * (17 * 512);              // u16 units
#pragma unroll
    for (int it = 0; it < 17; ++it)
      async16(Wsrc + base + it * 512 + lane * 8, Ws + base + it * 512);
  }
  __syncthreads();

  floatx16 acc[2][4] = {};
#pragma unroll 4
  for (int kk = 0; kk < NKI; ++kk) {
    bf16x8 a0 = pa0[kk & 3], a1 = pa1[kk & 3];
    if (kk + 4 < NKI) {
      pa0[kk & 3] = *(const bf16x8*)(Ap0 + (size_t)(kk + 4) * 512);
      pa1[kk & 3] = *(const bf16x8*)(Ap1 + (size_t)(kk + 4) * 512);
    }
    const u16* Bp = Ws + (2 * kk + hw) * 256 + ln * 8;
    bf16x8 b0 = *(const bf16x8*)(Bp);
    bf16x8 b1 = *(const bf16x8*)(Bp + 1 * KB8 * 256);
    bf16x8 b2 = *(const bf16x8*)(Bp + 2 * KB8 * 256);
    bf16x8 b3 = *(const bf16x8*)(Bp + 3 * KB8 * 256);
    acc[0][0] = __builtin_amdgcn_mfma_f32_32x32x16_bf16(a0, b0, acc[0][0], 0, 0, 0);
    acc[0][1] = __builtin_amdgcn_mfma_f32_32x32x16_bf16(a0, b1, acc[0][1], 0, 0, 0);
    acc[0][2] = __builtin_amdgcn_mfma_f32_32x32x16_bf16(a0, b2, acc[0][2], 0, 0, 0);
    acc[0][3] = __builtin_amdgcn_mfma_f32_32x32x16_bf16(a0, b3, acc[0][3], 0, 0, 0);
    acc[1][0] = __builtin_amdgcn_mfma_f32_32x32x16_bf16(a1, b0, acc[1][0], 0, 0, 0);
    acc[1][1] = __builtin_amdgcn_mfma_f32_32x32x16_bf16(a1, b1, acc[1][1], 0, 0, 0);
    acc[1][2] = __builtin_amdgcn_mfma_f32_32x32x16_bf16(a1, b2, acc[1][2], 0, 0, 0);
    acc[1][3] = __builtin_amdgcn_mfma_f32_32x32x16_bf16(a1, b3, acc[1][3], 0, 0, 0);
  }

  // ---- cell epilogue ----
  float bb[4];
#pragma unroll
  for (int j = 0; j < 4; ++j)
    bb[j] = brec[((z * 16 + nt) * 4 + j) * 32 + ln];

  const int hcol = nt * 32 + ln;
  const int last = (t == T_N - 1);
  u16* Aoz = Aout + zoff;

#pragma unroll
  for (int i = 0; i < 2; ++i) {
    const int mb = mblk0 + i;
    // c layout: [blk*8+wave][i][rg 4][lane 64] in float4 units — coalesced
    floatx4* C4 = (floatx4*)Cst + (((size_t)blk * 8 + wave) * 2 + i) * 256 + lane;
    floatx4 cv[4];
#pragma unroll
    for (int rg = 0; rg < 4; ++rg)
      cv[rg] = (t == 0) ? floatx4{0.f, 0.f, 0.f, 0.f} : C4[rg * 64];
#pragma unroll
    for (int r = 0; r < 16; ++r) {
      float pi = acc[i][0][r] + bb[0];
      float pf = acc[i][1][r] + bb[1];
      float pg = acc[i][2][r] + bb[2];
      float po = acc[i][3][r] + bb[3];
      float c = sigm(pf) * cv[r >> 2][r & 3] + sigm(pi) * tanhf_(pg);
      cv[r >> 2][r & 3] = c;
      u16 hb = f2bf(sigm(po) * tanhf_(c));
      // 32x32 C/D layout: col=lane&31, row=(r&3)+8*(r>>2)+4*(lane>>5)
      int mrow = 4 * hw + (r & 3) + 8 * (r >> 2);
      if (!last)
        Aoz[((size_t)mb * KB8 + (hcol >> 3)) * 256 + mrow * 8 + (hcol & 7)] = hb;
      else
        Hlast[((size_t)(z * B_N + mb * 32 + mrow)) * H_N + hcol] = hb;
    }
#pragma unroll
    for (int rg = 0; rg < 4; ++rg)
      C4[rg * 64] = cv[rg];
  }

  // ---- stage x_{t+1} slice (k in [512,540)) into Aout: nt==0 blocks only ----
  if (nt == 0 && t + 1 < T_N) {
    for (int idx = tid; idx < 512 * F_N; idx += 512) {
      int ml  = idx / F_N, col = idx - ml * F_N;
      int m   = mr * 512 + ml;
      int k   = H_N + col;
      Aoz[((size_t)(m >> 5) * KB8 + (k >> 3)) * 256 + (m & 31) * 8 + (k & 7)] =
          xb[(size_t)m * XP + (t + 1) * F_N + col];
    }
  }
}

// ============ generic GEMM (tail): C[z] = A[z] @ B[z]^T + bias[z] ============
template<int RELU, int OBF>
__global__ __launch_bounds__(256, 2)
void gemm_bt(const u16* __restrict__ A, int lda, long sAz,
             const u16* __restrict__ Bw, int ldb, long sBz,
             const float* __restrict__ bias, int sBiz,
             void* __restrict__ Cv, int ldc, long sCz,
             int K)
{
  __shared__ __align__(16) u16 As[128 * 32];
  __shared__ __align__(16) u16 Bs[128 * 32];
  const int tid  = threadIdx.x;
  const int lane = tid & 63;
  const int wave = tid >> 6;
  const int m0 = blockIdx.y * 128;
  const int n0 = blockIdx.x * 128;
  const int z  = blockIdx.z;
  const u16* Ab = A  + (size_t)z * sAz;
  const u16* Bb = Bw + (size_t)z * sBz;

  const int wm   = (wave & 1) * 64;
  const int wn   = (wave >> 1) * 64;
  const int lm   = lane & 15;
  const int quad = lane >> 4;

  const int s0 = wave * 64 + lane;
  const int r0 = s0 >> 2, c0 = (s0 & 3) * 8;
  const int s1 = s0 + 256;
  const int r1 = s1 >> 2, c1 = (s1 & 3) * 8;

  floatx4 acc[4][4] = {};

  for (int k0 = 0; k0 < K; k0 += 32) {
    async16(Ab + (size_t)(m0 + r0) * lda + (k0 + c0), As + wave * 512);
    async16(Ab + (size_t)(m0 + r1) * lda + (k0 + c1), As + 2048 + wave * 512);
    async16(Bb + (size_t)(n0 + r0) * ldb + (k0 + c0), Bs + wave * 512);
    async16(Bb + (size_t)(n0 + r1) * ldb + (k0 + c1), Bs + 2048 + wave * 512);
    __syncthreads();
    bf16x8 af[4], bf_[4];
#pragma unroll
    for (int i = 0; i < 4; ++i)
      af[i] = *(const bf16x8*)&As[(wm + i * 16 + lm) * 32 + quad * 8];
#pragma unroll
    for (int j = 0; j < 4; ++j)
      bf_[j] = *(const bf16x8*)&Bs[(wn + j * 16 + lm) * 32 + quad * 8];
#pragma unroll
    for (int i = 0; i < 4; ++i)
#pragma unroll
      for (int j = 0; j < 4; ++j)
        acc[i][j] = __builtin_amdgcn_mfma_f32_16x16x32_bf16(af[i], bf_[j], acc[i][j], 0, 0, 0);
    __syncthreads();
  }

  float bj[4];
#pragma unroll
  for (int j = 0; j < 4; ++j)
    bj[j] = bias ? bias[z * sBiz + n0 + wn + j * 16 + lm] : 0.f;

#pragma unroll
  for (int i = 0; i < 4; ++i) {
#pragma unroll
    for (int r = 0; r < 4; ++r) {
      int m = m0 + wm + i * 16 + quad * 4 + r;
      size_t row = (size_t)z * sCz + (size_t)m * ldc;
#pragma unroll
      for (int j = 0; j < 4; ++j) {
        int n = n0 + wn + j * 16 + lm;
        float v = acc[i][j][r] + bj[j];
        if (RELU) v = fmaxf(v, 0.f);
        if (OBF) ((u16*)Cv)[row + n] = f2bf(v);
        else     ((float*)Cv)[row + n] = v;
      }
    }
  }
}

// ============ gate: softmax(scores/e), top-5, renormalize. one wave per row ============
__global__ __launch_bounds__(256)
void gate_k(const float* __restrict__ x, const float* __restrict__ Wg,
            const float* __restrict__ bg, float* __restrict__ Wt)
{
  int lane = threadIdx.x & 63;
  int row  = blockIdx.x * 4 + (threadIdx.x >> 6);
  float ps[E_N];
#pragma unroll
  for (int e = 0; e < E_N; ++e) ps[e] = 0.f;
  const float* xr = x + (size_t)row * IN_N;
  for (int k = lane; k < IN_N; k += 64) {
    float xv = xr[k];
#pragma unroll
    for (int e = 0; e < E_N; ++e) ps[e] += xv * Wg[e * IN_N + k];
  }
#pragma unroll
  for (int e = 0; e < E_N; ++e) {
#pragma unroll
    for (int off = 32; off >= 1; off >>= 1) ps[e] += __shfl_down(ps[e], off);
  }
  if (lane == 0) {
    float s[E_N], mx = -1e30f;
#pragma unroll
    for (int e = 0; e < E_N; ++e) { s[e] = (ps[e] + bg[e]) * 0.36787944117144233f; mx = fmaxf(mx, s[e]); }
    float pr[E_N], sum = 0.f;
#pragma unroll
    for (int e = 0; e < E_N; ++e) { pr[e] = __expf(s[e] - mx); sum += pr[e]; }
    float inv = 1.f / sum;
#pragma unroll
    for (int e = 0; e < E_N; ++e) pr[e] *= inv;
    unsigned used = 0; float wsum = 0.f;
    for (int k = 0; k < 5; ++k) {
      int am = -1; float bv = -1.f;
      for (int e = 0; e < E_N; ++e)
        if (!((used >> e) & 1) && pr[e] > bv) { bv = pr[e]; am = e; }
      used |= 1u << am; wsum += pr[am];
    }
    float winv = 1.f / (wsum + 1e-8f);
    for (int e = 0; e < E_N; ++e)
      Wt[row * E_N + e] = ((used >> e) & 1) ? pr[e] * winv : 0.f;
  }
}

// ============ combine ============
__global__ __launch_bounds__(256)
void combine_k(const float* __restrict__ O, const float* __restrict__ Wt, float* __restrict__ out)
{
  int idx = blockIdx.x * 256 + threadIdx.x;
  if (idx >= B_N * OUT_N) return;
  int b = idx / OUT_N;
  float a = 0.f;
#pragma unroll
  for (int e = 0; e < E_N; ++e)
    a += Wt[b * E_N + e] * O[(size_t)e * B_N * OUT_N + idx];
  out[idx] = a;
}

// ============ prep kernels ============
__global__ void prep_x_k(const float* __restrict__ x, u16* __restrict__ xb) {
  int idx = blockIdx.x * 256 + threadIdx.x;
  if (idx >= B_N * XP) return;
  int k = idx % XP, b = idx / XP;
  xb[idx] = f2bf(k < IN_N ? x[(size_t)b * IN_N + k] : 0.f);
}
// W in B-frag layout: [z][nt][gate j 4][k8][ln 32][e8 8]; gate j holds h = 32*nt + ln
__global__ void prep_wfrag_k(const float* __restrict__ Whh, const float* __restrict__ Wih,
                             u16* __restrict__ Wc) {
  int idx = blockIdx.x * 256 + threadIdx.x;
  if (idx >= ER_N * G4H * KA) return;
  int e8 = idx & 7, ln = (idx >> 3) & 31;
  int k8 = (idx >> 8) % KB8;
  int rest = (idx >> 8) / KB8;
  int j = rest & 3, nt = (rest >> 2) & 15, z = rest >> 6;
  int h = nt * 32 + ln, k = k8 * 8 + e8;
  int g = j * H_N + h;
  float v = 0.f;
  if (k < H_N)            v = Whh[((size_t)(z * G4H + g)) * H_N + k];
  else if (k < H_N + F_N) v = Wih[((size_t)(z * G4H + g)) * F_N + (k - H_N)];
  Wc[idx] = f2bf(v);
}
__global__ void prep_bfrag_k(const float* __restrict__ bih, const float* __restrict__ bhh,
                             float* __restrict__ o) {
  int idx = blockIdx.x * 256 + threadIdx.x;
  if (idx >= ER_N * G4H) return;
  int ln = idx & 31, j = (idx >> 5) & 3, nt = (idx >> 7) & 15, z = idx >> 11;
  int g = z * G4H + j * H_N + nt * 32 + ln;
  o[idx] = bih[g] + bhh[g];
}
__global__ void cvt_k(const float* __restrict__ in, u16* __restrict__ o, int n) {
  int idx = blockIdx.x * 256 + threadIdx.x;
  if (idx < n) o[idx] = f2bf(in[idx]);
}
__global__ void prep_w1_k(const float* __restrict__ W1, u16* __restrict__ o) {
  int idx = blockIdx.x * 256 + threadIdx.x;
  if (idx >= ES_N * H_N * XP) return;
  int k = idx % XP; int r = idx / XP;
  o[idx] = f2bf(k < IN_N ? W1[(size_t)r * IN_N + k] : 0.f);
}
// A buffers in frag layout [z][mb 64][k8 68][mrow 32][e8 8]; A0 gets x_0, rest 0
__global__ void init_Afrag_k(u16* __restrict__ A0, u16* __restrict__ A1,
                             const u16* __restrict__ xb) {
  int idx = blockIdx.x * 256 + threadIdx.x;
  if (idx >= ER_N * B_N * KA) return;
  int e8 = idx & 7, mrow = (idx >> 3) & 31;
  int k8 = (idx >> 8) % KB8;
  int mb = ((idx >> 8) / KB8) & 63;
  int k = k8 * 8 + e8, m = mb * 32 + mrow;
  u16 v = 0;
  if (k >= H_N && k < H_N + F_N) v = xb[(size_t)m * XP + (k - H_N)];
  A0[idx] = v;
  A1[idx] = 0;
}

extern "C" void kernel_launch(void* const* d_in, const int* in_sizes, int n_in,
                              void* d_out, int out_size, void* d_ws, size_t ws_size,
                              hipStream_t stream) {
  const float* x   = (const float*)d_in[0];
  const float* Wg  = (const float*)d_in[1];
  const float* bg  = (const float*)d_in[2];
  const float* Wih = (const float*)d_in[3];
  const float* Whh = (const float*)d_in[4];
  const float* bih = (const float*)d_in[5];
  const float* bhh = (const float*)d_in[6];
  const float* fcW = (const float*)d_in[7];
  const float* fcb = (const float*)d_in[8];
  const float* W1  = (const float*)d_in[9];
  const float* b1  = (const float*)d_in[10];
  const float* W2  = (const float*)d_in[11];
  const float* b2  = (const float*)d_in[12];
  float* out = (float*)d_out;

  char* p = (char*)d_ws;
  auto take = [&](size_t bytes) { void* q = (void*)p; p += (bytes + 255) & ~(size_t)255; return q; };
  u16*   xb    = (u16*)  take((size_t)B_N * XP * 2);
  u16*   Wc    = (u16*)  take((size_t)ER_N * G4H * KA * 2);
  float* brec  = (float*)take((size_t)ER_N * G4H * 4);
  u16*   fcWb  = (u16*)  take((size_t)ER_N * OUT_N * H_N * 2);
  u16*   W1b   = (u16*)  take((size_t)ES_N * H_N * XP * 2);
  u16*   W2b   = (u16*)  take((size_t)ES_N * OUT_N * H_N * 2);
  u16*   A0    = (u16*)  take((size_t)ER_N * B_N * KA * 2);
  u16*   A1    = (u16*)  take((size_t)ER_N * B_N * KA * 2);
  float* Cst   = (float*)take((size_t)ER_N * B_N * H_N * 4);
  u16*   Hlast = (u16*)  take((size_t)ER_N * B_N * H_N * 2);
  u16*   H1    = (u16*)  take((size_t)ES_N * B_N * H_N * 2);
  float* Ob    = (float*)take((size_t)E_N * B_N * OUT_N * 4);
  float* Wgt   = (float*)take((size_t)B_N * E_N * 4);

  dim3 blk(256);
  prep_x_k    <<<CDIV(B_N * XP, 256),           blk, 0, stream>>>(x, xb);
  prep_wfrag_k<<<CDIV(ER_N * G4H * KA, 256),    blk, 0, stream>>>(Whh, Wih, Wc);
  prep_bfrag_k<<<CDIV(ER_N * G4H, 256),         blk, 0, stream>>>(bih, bhh, brec);
  cvt_k       <<<CDIV(ER_N * OUT_N * H_N, 256), blk, 0, stream>>>(fcW, fcWb, ER_N * OUT_N * H_N);
  prep_w1_k   <<<CDIV(ES_N * H_N * XP, 256),    blk, 0, stream>>>(W1, W1b);
  cvt_k       <<<CDIV(ES_N * OUT_N * H_N, 256), blk, 0, stream>>>(W2, W2b, ES_N * OUT_N * H_N);
  init_Afrag_k<<<CDIV(ER_N * B_N * KA, 256),    blk, 0, stream>>>(A0, A1, xb);
  gate_k      <<<B_N / 4,                       blk, 0, stream>>>(x, Wg, bg, Wgt);

  // ---- LSTM: 28 weight-stationary dispatches, ping-pong A ----
  constexpr unsigned ldsBytes = 4u * KB8 * 256u * 2u;   // 139264
  hipFuncSetAttribute((const void*)lstm_step,
                      hipFuncAttributeMaxDynamicSharedMemorySize, ldsBytes);
  for (int t = 0; t < T_N; ++t) {
    const u16* Ar = (t & 1) ? A1 : A0;
    u16*       Aw = (t & 1) ? A0 : A1;
    lstm_step<<<dim3(256), dim3(512), ldsBytes, stream>>>(
        Wc, brec, xb, Ar, Aw, Cst, Hlast, t);
  }

  // ---- fc on h_last -> Ob[0..3] ----
  gemm_bt<0, 0><<<dim3(OUT_N / 128, B_N / 128, ER_N), blk, 0, stream>>>(
      Hlast, H_N, (long)B_N * H_N,
      fcWb, H_N, (long)OUT_N * H_N,
      fcb, OUT_N,
      (void*)Ob, OUT_N, (long)B_N * OUT_N, H_N);

  // ---- simple experts ----
  gemm_bt<1, 1><<<dim3(H_N / 128, B_N / 128, ES_N), blk, 0, stream>>>(
      xb, XP, 0L,
      W1b, XP, (long)H_N * XP,
      b1, H_N,
      (void*)H1, H_N, (long)B_N * H_N, XP);
  gemm_bt<0, 0><<<dim3(OUT_N / 128, B_N / 128, ES_N), blk, 0, stream>>>(
      H1, H_N, (long)B_N * H_N,
      W2b, H_N, (long)OUT_N * H_N,
      b2, OUT_N,
      (void*)(Ob + (size_t)ER_N * B_N * OUT_N), OUT_N, (long)B_N * OUT_N, H_N);

  combine_k<<<CDIV(B_N * OUT_N, 256), blk, 0, stream>>>(Ob, Wgt, out);
}